// Round 2
// baseline (537.663 us; speedup 1.0000x reference)
//
#include <hip/hip_runtime.h>
#include <hip/hip_bf16.h>
#include <math.h>

// ---------------------------------------------------------------------------
// GraphAttentionLayer on MI355X.
// Math: softmax over (s_i + t_j) masked by adj  ==> s_i cancels row-wise.
//   e_j   = exp(t_j - gmax)
//   agg_i = (A @ (e*x))_i / (A @ e)_i          (A = adj as 0/1)
//   out   = elu(x + agg)
// => one dense bf16 MFMA GEMM  A[8192x8192] @ Y[8192x144]
//    Y cols 0..127 = e_j * x_j, col 128 = e_j, cols 129..143 = 0 (pad)
// ---------------------------------------------------------------------------

using f32x4  = __attribute__((ext_vector_type(4))) float;
using bf16x8 = __attribute__((ext_vector_type(8))) short;

#define N_NODES 8192
#define FIN     256
#define FOUT    128
#define NPAD    144
#define NSPLIT  8
#define KCHUNK  (N_NODES / NSPLIT)   // 1024

// workspace layout (bytes)
#define X_OFF    0u                                   // 8192*128 f32  = 4 MB
#define T_OFF    (X_OFF + N_NODES*FOUT*4u)            // 8192 f32
#define PMAX_OFF (T_OFF + N_NODES*4u)                 // 64 f32
#define GMAX_OFF (PMAX_OFF + 512u)                    // 1 f32
#define YT_OFF   (GMAX_OFF + 512u)                    // 144*8192 bf16 = 2.36 MB
#define P_OFF    (YT_OFF + (size_t)NPAD*N_NODES*2u)   // 8*8192*144 f32 = 37.7 MB

__device__ __forceinline__ unsigned short f2bf(float f) {
  unsigned int u = __float_as_uint(f);
  unsigned int r = (u + 0x7FFFu + ((u >> 16) & 1u)) >> 16;   // RNE
  return (unsigned short)r;
}

// ---- K1: x = input @ W_fc + b_fc  (f32 VALU GEMM, 16 rows/block) ----------
__global__ __launch_bounds__(256) void k1_fc(const float* __restrict__ in,
    const float* __restrict__ Wfc, const float* __restrict__ bfc,
    float* __restrict__ x) {
  __shared__ float sm[16 * FIN];
  const int tid = threadIdx.x;
  const int r0  = blockIdx.x * 16;
  const float4* gin = reinterpret_cast<const float4*>(in + (size_t)r0 * FIN);
  float4* sm4 = reinterpret_cast<float4*>(sm);
  #pragma unroll
  for (int i = 0; i < 4; i++) sm4[i * 256 + tid] = gin[i * 256 + tid];
  __syncthreads();
  const int d = tid & 127, g = tid >> 7;
  const float bias = bfc[d];
  float acc[8];
  #pragma unroll
  for (int r = 0; r < 8; r++) acc[r] = bias;
  const float4* s4 = reinterpret_cast<const float4*>(sm);
  for (int k = 0; k < FIN; k += 4) {
    float w0 = Wfc[(k + 0) * FOUT + d];
    float w1 = Wfc[(k + 1) * FOUT + d];
    float w2 = Wfc[(k + 2) * FOUT + d];
    float w3 = Wfc[(k + 3) * FOUT + d];
    #pragma unroll
    for (int r = 0; r < 8; r++) {
      float4 iv = s4[((g * 8 + r) * FIN + k) >> 2];
      acc[r] = fmaf(iv.x, w0, acc[r]);
      acc[r] = fmaf(iv.y, w1, acc[r]);
      acc[r] = fmaf(iv.z, w2, acc[r]);
      acc[r] = fmaf(iv.w, w3, acc[r]);
    }
  }
  #pragma unroll
  for (int r = 0; r < 8; r++)
    x[(size_t)(r0 + g * 8 + r) * FOUT + d] = acc[r];
}

// ---- K2: t_j = x_j . w_an + b_an ; per-block max -> pmax ------------------
__global__ __launch_bounds__(256) void k2_att(const float* __restrict__ x,
    const float* __restrict__ wan, const float* __restrict__ ban,
    float* __restrict__ t, float* __restrict__ pmax) {
  __shared__ float wm[4];
  const int tid = threadIdx.x, lane = tid & 63, w = tid >> 6;
  const float w0 = wan[lane], w1 = wan[lane + 64];
  const float bb = ban[0];
  float tmax = -1e30f;
  const int rbase = blockIdx.x * 128 + w * 32;
  for (int rr = 0; rr < 32; rr++) {
    const int row = rbase + rr;
    float p = x[(size_t)row * FOUT + lane] * w0
            + x[(size_t)row * FOUT + 64 + lane] * w1;
    #pragma unroll
    for (int m = 1; m < 64; m <<= 1) p += __shfl_xor(p, m);
    const float tv = p + bb;
    if (lane == 0) t[row] = tv;
    tmax = fmaxf(tmax, tv);
  }
  if (lane == 0) wm[w] = tmax;
  __syncthreads();
  if (tid == 0)
    pmax[blockIdx.x] = fmaxf(fmaxf(wm[0], wm[1]), fmaxf(wm[2], wm[3]));
}

// ---- K3: gmax = max(pmax[0..63]) ------------------------------------------
__global__ void k3_gmax(const float* __restrict__ pmax, float* __restrict__ gmax) {
  float v = pmax[threadIdx.x];
  #pragma unroll
  for (int m = 1; m < 64; m <<= 1) v = fmaxf(v, __shfl_xor(v, m));
  if (threadIdx.x == 0) gmax[0] = v;
}

// ---- K4: build Y^T [144][8192] bf16 ---------------------------------------
__global__ __launch_bounds__(256) void k4_y(const float* __restrict__ x,
    const float* __restrict__ t, const float* __restrict__ gmax,
    unsigned short* __restrict__ Yt) {
  const int tid = threadIdx.x, lane = tid & 63, w = tid >> 6;
  const int j = blockIdx.x * 64 + lane;
  const float e = expf(t[j] - gmax[0]);
  const float4* x4 = reinterpret_cast<const float4*>(x + (size_t)j * FOUT + w * 32);
  #pragma unroll
  for (int dd = 0; dd < 8; dd++) {
    float4 xv = x4[dd];
    const int d = w * 32 + dd * 4;
    Yt[(size_t)(d + 0) * N_NODES + j] = f2bf(e * xv.x);
    Yt[(size_t)(d + 1) * N_NODES + j] = f2bf(e * xv.y);
    Yt[(size_t)(d + 2) * N_NODES + j] = f2bf(e * xv.z);
    Yt[(size_t)(d + 3) * N_NODES + j] = f2bf(e * xv.w);
  }
  if (w == 0) {
    Yt[(size_t)128 * N_NODES + j] = f2bf(e);
    #pragma unroll
    for (int r = 129; r < NPAD; r++) Yt[(size_t)r * N_NODES + j] = 0;
  }
}

// ---- K5: P[s] = A[:, chunk_s] @ Y[chunk_s, :]   (bf16 MFMA, split-K) ------
// BM=64 (4 waves x 16 rows), BN=144 (9 n-frags), A int->bf16 inline.
__global__ __launch_bounds__(256) void k5_gemm(const int* __restrict__ adj,
    const unsigned short* __restrict__ Yt, float* __restrict__ P) {
  const int tid  = threadIdx.x;
  const int lane = tid & 63, w = tid >> 6;
  const int bm = blockIdx.x, s = blockIdx.y;
  const int q  = lane >> 4;                       // 0..3
  const int arow = bm * 64 + w * 16 + (lane & 15);
  const int* aptr = adj + (size_t)arow * N_NODES + s * KCHUNK + q * 8;
  const unsigned short* bbase =
      Yt + (size_t)(lane & 15) * N_NODES + s * KCHUNK + q * 8;

  f32x4 acc[9];
  #pragma unroll
  for (int nf = 0; nf < 9; nf++) acc[nf] = (f32x4){0.f, 0.f, 0.f, 0.f};

  for (int k = 0; k < KCHUNK; k += 32) {
    int4 a0 = *reinterpret_cast<const int4*>(aptr + k);
    int4 a1 = *reinterpret_cast<const int4*>(aptr + k + 4);
    union { bf16x8 v; unsigned int u[4]; } af;
    af.u[0] = (unsigned int)(a0.x | (a0.y << 16)) * 0x3F80u;
    af.u[1] = (unsigned int)(a0.z | (a0.w << 16)) * 0x3F80u;
    af.u[2] = (unsigned int)(a1.x | (a1.y << 16)) * 0x3F80u;
    af.u[3] = (unsigned int)(a1.z | (a1.w << 16)) * 0x3F80u;
    bf16x8 bf[9];
    #pragma unroll
    for (int nf = 0; nf < 9; nf++)
      bf[nf] = *reinterpret_cast<const bf16x8*>(bbase + (size_t)nf * 16 * N_NODES + k);
    #pragma unroll
    for (int nf = 0; nf < 9; nf++)
      acc[nf] = __builtin_amdgcn_mfma_f32_16x16x32_bf16(af.v, bf[nf], acc[nf], 0, 0, 0);
  }

  float* Pp = P + (size_t)s * N_NODES * NPAD;
  const int colb = lane & 15;
  #pragma unroll
  for (int nf = 0; nf < 9; nf++) {
    // nf==8 covers cols 128..143; only col 128 (Z) is ever read — skip pads.
    if (nf == 8 && colb != 0) continue;
    #pragma unroll
    for (int r = 0; r < 4; r++) {
      const int grow = bm * 64 + w * 16 + q * 4 + r;   // C/D: row=(lane>>4)*4+r
      Pp[(size_t)grow * NPAD + nf * 16 + colb] = acc[nf][r];
    }
  }
}

// ---- K6: reduce split-K, divide, residual, ELU ----------------------------
__global__ __launch_bounds__(256) void k6_fin(const float* __restrict__ P,
    const float* __restrict__ x, float* __restrict__ out) {
  const int gid = blockIdx.x * 256 + threadIdx.x;
  const int i = gid >> 7, d = gid & 127;
  const size_t base = (size_t)i * NPAD;
  float num = 0.f, Z = 0.f;
  #pragma unroll
  for (int s = 0; s < NSPLIT; s++) {
    num += P[(size_t)s * N_NODES * NPAD + base + d];
    Z   += P[(size_t)s * N_NODES * NPAD + base + 128];
  }
  const float agg = (Z > 0.f) ? num / Z : 0.f;   // empty row never occurs here
  const float v = x[(size_t)i * FOUT + d] + agg;
  out[gid] = (v > 0.f) ? v : expm1f(v);
}

extern "C" void kernel_launch(void* const* d_in, const int* in_sizes, int n_in,
                              void* d_out, int out_size, void* d_ws, size_t ws_size,
                              hipStream_t stream) {
  const float* input = (const float*)d_in[0];
  const int*   adj   = (const int*)d_in[1];
  const float* Wfc   = (const float*)d_in[2];
  const float* bfc   = (const float*)d_in[3];
  // d_in[4], d_in[5] (w_ax, b_ax) cancel in the row softmax — unused.
  const float* wan   = (const float*)d_in[6];
  const float* ban   = (const float*)d_in[7];

  char* ws = (char*)d_ws;
  float*          x    = (float*)(ws + X_OFF);
  float*          t    = (float*)(ws + T_OFF);
  float*          pmax = (float*)(ws + PMAX_OFF);
  float*          gmax = (float*)(ws + GMAX_OFF);
  unsigned short* Yt   = (unsigned short*)(ws + YT_OFF);
  float*          P    = (float*)(ws + P_OFF);
  float*          out  = (float*)d_out;

  k1_fc  <<<dim3(512),        dim3(256), 0, stream>>>(input, Wfc, bfc, x);
  k2_att <<<dim3(64),         dim3(256), 0, stream>>>(x, wan, ban, t, pmax);
  k3_gmax<<<dim3(1),          dim3(64),  0, stream>>>(pmax, gmax);
  k4_y   <<<dim3(128),        dim3(256), 0, stream>>>(x, t, gmax, Yt);
  k5_gemm<<<dim3(128, NSPLIT),dim3(256), 0, stream>>>(adj, Yt, P);
  k6_fin <<<dim3(4096),       dim3(256), 0, stream>>>(P, x, out);
}

// Round 3
// 481.999 us; speedup vs baseline: 1.1155x; 1.1155x over previous
//
#include <hip/hip_runtime.h>
#include <hip/hip_bf16.h>
#include <math.h>

// ---------------------------------------------------------------------------
// GraphAttentionLayer on MI355X.
// Math: softmax over (s_i + t_j) masked by adj  ==> s_i cancels row-wise.
//   e_j   = exp(t_j - gmax)
//   agg_i = (A @ (e*x))_i / (A @ e)_i          (A = adj as 0/1)
//   out   = elu(x + agg)
// => one dense bf16 MFMA GEMM  A[8192x8192] @ Y[8192x144], split-K=8.
// Y is stored PRE-PACKED in MFMA B-fragment order:
//   Yf[window W][nf][lane][e]  (W = k/32, nf = col/16, lane = q*16+(col&15),
//   e = k&7, q = (k>>3)&3)  -> each wave B-load is one contiguous 1KB chunk.
// ---------------------------------------------------------------------------

using f32x4  = __attribute__((ext_vector_type(4))) float;
using bf16x8 = __attribute__((ext_vector_type(8))) short;

#define N_NODES 8192
#define FIN     256
#define FOUT    128
#define NPAD    144
#define NSPLIT  8
#define KCHUNK  (N_NODES / NSPLIT)   // 1024

// workspace layout (bytes)
#define X_OFF    0u                                   // 8192*128 f32  = 4 MB
#define T_OFF    (X_OFF + N_NODES*FOUT*4u)            // 8192 f32
#define PMAX_OFF (T_OFF + N_NODES*4u)                 // 256 f32
#define GMAX_OFF (PMAX_OFF + 1024u)                   // 1 f32
#define YT_OFF   (GMAX_OFF + 512u)                    // 144*8192 bf16 = 2.36 MB
#define P_OFF    (YT_OFF + (size_t)NPAD*N_NODES*2u)   // 8*8192*144 f32 = 37.7 MB

__device__ __forceinline__ unsigned short f2bf(float f) {
  unsigned int u = __float_as_uint(f);
  unsigned int r = (u + 0x7FFFu + ((u >> 16) & 1u)) >> 16;   // RNE
  return (unsigned short)r;
}

// ---- K1: x = input @ W_fc + b_fc  (f32 VALU GEMM, 16 rows/block) ----------
__global__ __launch_bounds__(256) void k1_fc(const float* __restrict__ in,
    const float* __restrict__ Wfc, const float* __restrict__ bfc,
    float* __restrict__ x) {
  __shared__ float sm[16 * FIN];
  const int tid = threadIdx.x;
  const int r0  = blockIdx.x * 16;
  const float4* gin = reinterpret_cast<const float4*>(in + (size_t)r0 * FIN);
  float4* sm4 = reinterpret_cast<float4*>(sm);
  #pragma unroll
  for (int i = 0; i < 4; i++) sm4[i * 256 + tid] = gin[i * 256 + tid];
  __syncthreads();
  const int d = tid & 127, g = tid >> 7;
  const float bias = bfc[d];
  float acc[8];
  #pragma unroll
  for (int r = 0; r < 8; r++) acc[r] = bias;
  const float4* s4 = reinterpret_cast<const float4*>(sm);
  for (int k = 0; k < FIN; k += 4) {
    float w0 = Wfc[(k + 0) * FOUT + d];
    float w1 = Wfc[(k + 1) * FOUT + d];
    float w2 = Wfc[(k + 2) * FOUT + d];
    float w3 = Wfc[(k + 3) * FOUT + d];
    #pragma unroll
    for (int r = 0; r < 8; r++) {
      float4 iv = s4[((g * 8 + r) * FIN + k) >> 2];
      acc[r] = fmaf(iv.x, w0, acc[r]);
      acc[r] = fmaf(iv.y, w1, acc[r]);
      acc[r] = fmaf(iv.z, w2, acc[r]);
      acc[r] = fmaf(iv.w, w3, acc[r]);
    }
  }
  #pragma unroll
  for (int r = 0; r < 8; r++)
    x[(size_t)(r0 + g * 8 + r) * FOUT + d] = acc[r];
}

// ---- K2: t_j = x_j . w_an + b_an ; per-block max -> pmax (256 blocks) -----
__global__ __launch_bounds__(256) void k2_att(const float* __restrict__ x,
    const float* __restrict__ wan, const float* __restrict__ ban,
    float* __restrict__ t, float* __restrict__ pmax) {
  __shared__ float wm[4];
  const int tid = threadIdx.x, lane = tid & 63, w = tid >> 6;
  const float w0 = wan[lane], w1 = wan[lane + 64];
  const float bb = ban[0];
  float tmax = -1e30f;
  const int rbase = blockIdx.x * 32 + w * 8;
  for (int rr = 0; rr < 8; rr++) {
    const int row = rbase + rr;
    float p = x[(size_t)row * FOUT + lane] * w0
            + x[(size_t)row * FOUT + 64 + lane] * w1;
    #pragma unroll
    for (int m = 1; m < 64; m <<= 1) p += __shfl_xor(p, m);
    const float tv = p + bb;
    if (lane == 0) t[row] = tv;
    tmax = fmaxf(tmax, tv);
  }
  if (lane == 0) wm[w] = tmax;
  __syncthreads();
  if (tid == 0)
    pmax[blockIdx.x] = fmaxf(fmaxf(wm[0], wm[1]), fmaxf(wm[2], wm[3]));
}

// ---- K3: gmax = max(pmax[0..255]) -----------------------------------------
__global__ void k3_gmax(const float* __restrict__ pmax, float* __restrict__ gmax) {
  float v = fmaxf(fmaxf(pmax[threadIdx.x], pmax[threadIdx.x + 64]),
                  fmaxf(pmax[threadIdx.x + 128], pmax[threadIdx.x + 192]));
  #pragma unroll
  for (int m = 1; m < 64; m <<= 1) v = fmaxf(v, __shfl_xor(v, m));
  if (threadIdx.x == 0) gmax[0] = v;
}

// ---- K4: build Yf in MFMA B-fragment order via LDS transpose --------------
// Block = 64 nodes (2 k-windows). LDS holds Y[c][jj] (144 x 64 bf16 = 18KB).
__global__ __launch_bounds__(256) void k4_y(const float* __restrict__ x,
    const float* __restrict__ t, const float* __restrict__ gmax,
    unsigned short* __restrict__ Yf) {
  __shared__ unsigned short sm[NPAD * 64];
  const int tid = threadIdx.x, lane = tid & 63, w = tid >> 6;
  const int jj = lane, j = blockIdx.x * 64 + jj;
  const float e = expf(t[j] - gmax[0]);
  const float4* x4 = reinterpret_cast<const float4*>(x + (size_t)j * FOUT + w * 32);
  #pragma unroll
  for (int dd = 0; dd < 8; dd++) {
    float4 xv = x4[dd];
    const int c = w * 32 + dd * 4;
    sm[(c + 0) * 64 + jj] = f2bf(e * xv.x);
    sm[(c + 1) * 64 + jj] = f2bf(e * xv.y);
    sm[(c + 2) * 64 + jj] = f2bf(e * xv.z);
    sm[(c + 3) * 64 + jj] = f2bf(e * xv.w);
  }
  #pragma unroll
  for (int i = 0; i < 4; i++) {     // cols 128..143: e in col 128, pads 0
    const int c = 128 + w * 4 + i;
    sm[c * 64 + jj] = (c == 128) ? f2bf(e) : (unsigned short)0;
  }
  __syncthreads();
  // 18 chunks (2 windows x 9 nf), each = contiguous 1KB in Yf.
  for (int c5 = w; c5 < 18; c5 += 4) {
    const int wnd = c5 / 9, nf = c5 % 9;
    const int srcIdx = (nf * 16 + (lane & 15)) * 64 + wnd * 32 + (lane >> 4) * 8;
    bf16x8 v = *reinterpret_cast<const bf16x8*>(&sm[srcIdx]);
    const size_t Wg = (size_t)blockIdx.x * 2 + wnd;
    *reinterpret_cast<bf16x8*>(Yf + (Wg * 9 + nf) * 512 + lane * 8) = v;
  }
}

// ---- K5: P[s] = A[:, chunk_s] @ Y[chunk_s, :]   (bf16 MFMA, split-K) ------
// BM=64 (4 waves x 16 rows), BN=144 (9 n-frags).
// A int->bf16 inline; depth-2 register pipeline on A; B loads contiguous 1KB.
__global__ __launch_bounds__(256) void k5_gemm(const int* __restrict__ adj,
    const unsigned short* __restrict__ Yf, float* __restrict__ P) {
  const int tid  = threadIdx.x;
  const int lane = tid & 63, w = tid >> 6;
  const int bm = blockIdx.x, s = blockIdx.y;
  const int q  = lane >> 4;                       // 0..3
  const int arow = bm * 64 + w * 16 + (lane & 15);
  const int* aptr = adj + (size_t)arow * N_NODES + s * KCHUNK + q * 8;
  const unsigned short* bptr = Yf + ((size_t)s * (KCHUNK / 32) * 9) * 512 + lane * 8;

  f32x4 acc[9];
  #pragma unroll
  for (int nf = 0; nf < 9; nf++) acc[nf] = (f32x4){0.f, 0.f, 0.f, 0.f};

#define LOAD_A(dst0, dst1, kk_) \
    dst0 = *reinterpret_cast<const int4*>(aptr + (kk_)); \
    dst1 = *reinterpret_cast<const int4*>(aptr + (kk_) + 4);

#define CONV_MFMA(a0_, a1_, kk_) { \
    bf16x8 bf[9]; \
    const unsigned short* bw = bptr + (size_t)((kk_) >> 5) * 9 * 512; \
    _Pragma("unroll") \
    for (int nf = 0; nf < 9; nf++) \
      bf[nf] = *reinterpret_cast<const bf16x8*>(bw + nf * 512); \
    union { bf16x8 v; unsigned int u[4]; } af; \
    af.u[0] = (unsigned int)((a0_).x | ((a0_).y << 16)) * 0x3F80u; \
    af.u[1] = (unsigned int)((a0_).z | ((a0_).w << 16)) * 0x3F80u; \
    af.u[2] = (unsigned int)((a1_).x | ((a1_).y << 16)) * 0x3F80u; \
    af.u[3] = (unsigned int)((a1_).z | ((a1_).w << 16)) * 0x3F80u; \
    _Pragma("unroll") \
    for (int nf = 0; nf < 9; nf++) \
      acc[nf] = __builtin_amdgcn_mfma_f32_16x16x32_bf16(af.v, bf[nf], acc[nf], 0, 0, 0); \
  }

  int4 A0a, A0b, A1a, A1b, A2a, A2b, A3a, A3b;
  LOAD_A(A0a, A0b, 0);
  LOAD_A(A1a, A1b, 32);
  // main: kk = 0, 64, ..., 896  (prefetch kk+64, kk+96 each iter)
  for (int kk = 0; kk <= KCHUNK - 128; kk += 64) {
    LOAD_A(A2a, A2b, kk + 64);
    CONV_MFMA(A0a, A0b, kk);
    LOAD_A(A3a, A3b, kk + 96);
    CONV_MFMA(A1a, A1b, kk + 32);
    A0a = A2a; A0b = A2b; A1a = A3a; A1b = A3b;
  }
  // epilogue: kk = 960 window pair
  CONV_MFMA(A0a, A0b, KCHUNK - 64);
  CONV_MFMA(A1a, A1b, KCHUNK - 32);
#undef LOAD_A
#undef CONV_MFMA

  float* Pp = P + (size_t)s * N_NODES * NPAD;
  const int colb = lane & 15;
  #pragma unroll
  for (int nf = 0; nf < 9; nf++) {
    // nf==8 covers cols 128..143; only col 128 (Z) is ever read — skip pads.
    if (nf == 8 && colb != 0) continue;
    #pragma unroll
    for (int r = 0; r < 4; r++) {
      const int grow = bm * 64 + w * 16 + q * 4 + r;   // C/D: row=(lane>>4)*4+r
      Pp[(size_t)grow * NPAD + nf * 16 + colb] = acc[nf][r];
    }
  }
}

// ---- K6: reduce split-K, divide, residual, ELU ----------------------------
__global__ __launch_bounds__(256) void k6_fin(const float* __restrict__ P,
    const float* __restrict__ x, float* __restrict__ out) {
  const int gid = blockIdx.x * 256 + threadIdx.x;
  const int i = gid >> 7, d = gid & 127;
  const size_t base = (size_t)i * NPAD;
  float num = 0.f, Z = 0.f;
  #pragma unroll
  for (int s = 0; s < NSPLIT; s++) {
    num += P[(size_t)s * N_NODES * NPAD + base + d];
    Z   += P[(size_t)s * N_NODES * NPAD + base + 128];
  }
  const float agg = (Z > 0.f) ? num / Z : 0.f;   // empty row never occurs here
  const float v = x[(size_t)i * FOUT + d] + agg;
  out[gid] = (v > 0.f) ? v : expm1f(v);
}

extern "C" void kernel_launch(void* const* d_in, const int* in_sizes, int n_in,
                              void* d_out, int out_size, void* d_ws, size_t ws_size,
                              hipStream_t stream) {
  const float* input = (const float*)d_in[0];
  const int*   adj   = (const int*)d_in[1];
  const float* Wfc   = (const float*)d_in[2];
  const float* bfc   = (const float*)d_in[3];
  // d_in[4], d_in[5] (w_ax, b_ax) cancel in the row softmax — unused.
  const float* wan   = (const float*)d_in[6];
  const float* ban   = (const float*)d_in[7];

  char* ws = (char*)d_ws;
  float*          x    = (float*)(ws + X_OFF);
  float*          t    = (float*)(ws + T_OFF);
  float*          pmax = (float*)(ws + PMAX_OFF);
  float*          gmax = (float*)(ws + GMAX_OFF);
  unsigned short* Yf   = (unsigned short*)(ws + YT_OFF);
  float*          P    = (float*)(ws + P_OFF);
  float*          out  = (float*)d_out;

  k1_fc  <<<dim3(512),         dim3(256), 0, stream>>>(input, Wfc, bfc, x);
  k2_att <<<dim3(256),         dim3(256), 0, stream>>>(x, wan, ban, t, pmax);
  k3_gmax<<<dim3(1),           dim3(64),  0, stream>>>(pmax, gmax);
  k4_y   <<<dim3(128),         dim3(256), 0, stream>>>(x, t, gmax, Yf);
  k5_gemm<<<dim3(128, NSPLIT), dim3(256), 0, stream>>>(adj, Yf, P);
  k6_fin <<<dim3(4096),        dim3(256), 0, stream>>>(P, x, out);
}

// Round 5
// 459.412 us; speedup vs baseline: 1.1703x; 1.0492x over previous
//
#include <hip/hip_runtime.h>
#include <hip/hip_bf16.h>
#include <math.h>

// ---------------------------------------------------------------------------
// GraphAttentionLayer on MI355X.
// Math: softmax over (s_i + t_j) masked by adj  ==> s_i cancels row-wise.
//   e_j   = exp(t_j - gmax)
//   agg_i = (A @ (e*x))_i / (A @ e)_i          (A = adj as 0/1)
//   out   = elu(x + agg)
// => one dense bf16 MFMA GEMM  A[8192x8192] @ Y[8192x144], split-K=8.
// Y pre-packed in MFMA B-fragment order (1KB contiguous per wave-load).
// K5: A staged global->LDS via global_load_lds (coalesced, XOR-swizzled),
//     B prefetched into registers 2 windows ahead (counted vmcnt friendly).
// ---------------------------------------------------------------------------

using f32x4  = __attribute__((ext_vector_type(4))) float;
using bf16x8 = __attribute__((ext_vector_type(8))) short;

#define N_NODES 8192
#define FIN     256
#define FOUT    128
#define NPAD    144
#define NSPLIT  8
#define KCHUNK  (N_NODES / NSPLIT)   // 1024

// workspace layout (bytes)
#define X_OFF    0u                                   // 8192*128 f32  = 4 MB
#define T_OFF    (X_OFF + N_NODES*FOUT*4u)            // 8192 f32
#define PMAX_OFF (T_OFF + N_NODES*4u)                 // 256 f32
#define GMAX_OFF (PMAX_OFF + 1024u)                   // 1 f32
#define YT_OFF   (GMAX_OFF + 512u)                    // 144*8192 bf16 = 2.36 MB
#define P_OFF    (YT_OFF + (size_t)NPAD*N_NODES*2u)   // 8*8192*144 f32 = 37.7 MB

__device__ __forceinline__ unsigned short f2bf(float f) {
  unsigned int u = __float_as_uint(f);
  unsigned int r = (u + 0x7FFFu + ((u >> 16) & 1u)) >> 16;   // RNE
  return (unsigned short)r;
}

__device__ __forceinline__ void gload_lds16(const void* gsrc, void* ldst) {
  __builtin_amdgcn_global_load_lds(
      (const __attribute__((address_space(1))) void*)gsrc,
      (__attribute__((address_space(3))) void*)ldst, 16, 0, 0);
}

// ---- K1: x = input @ W_fc + b_fc  (f32 VALU GEMM, 16 rows/block) ----------
__global__ __launch_bounds__(256) void k1_fc(const float* __restrict__ in,
    const float* __restrict__ Wfc, const float* __restrict__ bfc,
    float* __restrict__ x) {
  __shared__ float sm[16 * FIN];
  const int tid = threadIdx.x;
  const int r0  = blockIdx.x * 16;
  const float4* gin = reinterpret_cast<const float4*>(in + (size_t)r0 * FIN);
  float4* sm4 = reinterpret_cast<float4*>(sm);
  #pragma unroll
  for (int i = 0; i < 4; i++) sm4[i * 256 + tid] = gin[i * 256 + tid];
  __syncthreads();
  const int d = tid & 127, g = tid >> 7;
  const float bias = bfc[d];
  float acc[8];
  #pragma unroll
  for (int r = 0; r < 8; r++) acc[r] = bias;
  const float4* s4 = reinterpret_cast<const float4*>(sm);
  for (int k = 0; k < FIN; k += 4) {
    float w0 = Wfc[(k + 0) * FOUT + d];
    float w1 = Wfc[(k + 1) * FOUT + d];
    float w2 = Wfc[(k + 2) * FOUT + d];
    float w3 = Wfc[(k + 3) * FOUT + d];
    #pragma unroll
    for (int r = 0; r < 8; r++) {
      float4 iv = s4[((g * 8 + r) * FIN + k) >> 2];
      acc[r] = fmaf(iv.x, w0, acc[r]);
      acc[r] = fmaf(iv.y, w1, acc[r]);
      acc[r] = fmaf(iv.z, w2, acc[r]);
      acc[r] = fmaf(iv.w, w3, acc[r]);
    }
  }
  #pragma unroll
  for (int r = 0; r < 8; r++)
    x[(size_t)(r0 + g * 8 + r) * FOUT + d] = acc[r];
}

// ---- K2: t_j = x_j . w_an + b_an ; per-block max -> pmax (256 blocks) -----
__global__ __launch_bounds__(256) void k2_att(const float* __restrict__ x,
    const float* __restrict__ wan, const float* __restrict__ ban,
    float* __restrict__ t, float* __restrict__ pmax) {
  __shared__ float wm[4];
  const int tid = threadIdx.x, lane = tid & 63, w = tid >> 6;
  const float w0 = wan[lane], w1 = wan[lane + 64];
  const float bb = ban[0];
  float tmax = -1e30f;
  const int rbase = blockIdx.x * 32 + w * 8;
  for (int rr = 0; rr < 8; rr++) {
    const int row = rbase + rr;
    float p = x[(size_t)row * FOUT + lane] * w0
            + x[(size_t)row * FOUT + 64 + lane] * w1;
    #pragma unroll
    for (int m = 1; m < 64; m <<= 1) p += __shfl_xor(p, m);
    const float tv = p + bb;
    if (lane == 0) t[row] = tv;
    tmax = fmaxf(tmax, tv);
  }
  if (lane == 0) wm[w] = tmax;
  __syncthreads();
  if (tid == 0)
    pmax[blockIdx.x] = fmaxf(fmaxf(wm[0], wm[1]), fmaxf(wm[2], wm[3]));
}

// ---- K3: gmax = max(pmax[0..255]) -----------------------------------------
__global__ void k3_gmax(const float* __restrict__ pmax, float* __restrict__ gmax) {
  float v = fmaxf(fmaxf(pmax[threadIdx.x], pmax[threadIdx.x + 64]),
                  fmaxf(pmax[threadIdx.x + 128], pmax[threadIdx.x + 192]));
  #pragma unroll
  for (int m = 1; m < 64; m <<= 1) v = fmaxf(v, __shfl_xor(v, m));
  if (threadIdx.x == 0) gmax[0] = v;
}

// ---- K4: build Yf in MFMA B-fragment order via LDS transpose --------------
__global__ __launch_bounds__(256) void k4_y(const float* __restrict__ x,
    const float* __restrict__ t, const float* __restrict__ gmax,
    unsigned short* __restrict__ Yf) {
  __shared__ unsigned short sm[NPAD * 64];
  const int tid = threadIdx.x, lane = tid & 63, w = tid >> 6;
  const int jj = lane, j = blockIdx.x * 64 + jj;
  const float e = expf(t[j] - gmax[0]);
  const float4* x4 = reinterpret_cast<const float4*>(x + (size_t)j * FOUT + w * 32);
  #pragma unroll
  for (int dd = 0; dd < 8; dd++) {
    float4 xv = x4[dd];
    const int c = w * 32 + dd * 4;
    sm[(c + 0) * 64 + jj] = f2bf(e * xv.x);
    sm[(c + 1) * 64 + jj] = f2bf(e * xv.y);
    sm[(c + 2) * 64 + jj] = f2bf(e * xv.z);
    sm[(c + 3) * 64 + jj] = f2bf(e * xv.w);
  }
  #pragma unroll
  for (int i = 0; i < 4; i++) {     // cols 128..143: e in col 128, pads 0
    const int c = 128 + w * 4 + i;
    sm[c * 64 + jj] = (c == 128) ? f2bf(e) : (unsigned short)0;
  }
  __syncthreads();
  for (int c5 = w; c5 < 18; c5 += 4) {
    const int wnd = c5 / 9, nf = c5 % 9;
    const int srcIdx = (nf * 16 + (lane & 15)) * 64 + wnd * 32 + (lane >> 4) * 8;
    bf16x8 v = *reinterpret_cast<const bf16x8*>(&sm[srcIdx]);
    const size_t Wg = (size_t)blockIdx.x * 2 + wnd;
    *reinterpret_cast<bf16x8*>(Yf + (Wg * 9 + nf) * 512 + lane * 8) = v;
  }
}

// ---- K5: P[s] = A[:, chunk_s] @ Y[chunk_s, :]   (bf16 MFMA, split-K) ------
// BM=64 (4 waves x 16 rows), BN=144 (9 n-frags).
// A: global_load_lds -> LDS[2][64x64 int], XOR-swizzled (src-preswizzle).
// B: register prefetch 2 windows ahead. One barrier per 64-k tile.
__global__ __launch_bounds__(256) void k5_gemm(const int* __restrict__ adj,
    const unsigned short* __restrict__ Yf, float* __restrict__ P) {
  __shared__ int ldsA[2][64 * 64];
  const int tid  = threadIdx.x;
  const int lane = tid & 63, w = tid >> 6;
  const int bm = blockIdx.x, s = blockIdx.y;
  const int q  = lane >> 4;                       // 0..3
  const int rsub = lane >> 4, cb16 = (lane & 15) << 4;
  const unsigned short* bbase = Yf + (size_t)s * 32 * 9 * 512 + lane * 8;

  f32x4 acc[9];
  #pragma unroll
  for (int nf = 0; nf < 9; nf++) acc[nf] = (f32x4){0.f, 0.f, 0.f, 0.f};

  // ---- helpers as macros (static unroll, named regs) ----
#define STAGE_A(kbase_, buf_) { \
    _Pragma("unroll") \
    for (int i = 0; i < 4; i++) { \
      const int rit = w * 16 + i * 4 + rsub; \
      const int gcb = cb16 ^ ((rit & 7) << 4); \
      const char* gsrc = (const char*)adj + (((size_t)(bm * 64 + rit)) << 15) \
                       + (size_t)(s * KCHUNK + (kbase_)) * 4 + gcb; \
      gload_lds16(gsrc, (char*)&ldsA[buf_][(w * 16 + i * 4) * 64]); \
    } }

#define LOAD_B(dst_, wnd_) { \
    const unsigned short* p_ = bbase + (size_t)(wnd_) * 9 * 512; \
    _Pragma("unroll") \
    for (int nf = 0; nf < 9; nf++) \
      dst_[nf] = *reinterpret_cast<const bf16x8*>(p_ + nf * 512); \
  }

  // FIX (R4 bug): LDS row must include the wave's 16-row offset (w*16).
  // R4 read row (lane&15) — waves 1..3 consumed wave 0's adjacency rows.
#define AFRAG(buf_, kk_, a0_, a1_) { \
    const int r_ = lane & 15; \
    const int sw_ = (r_ & 7) << 4; \
    const char* rowb_ = (const char*)&ldsA[buf_][(w * 16 + r_) * 64]; \
    const int cb0_ = ((kk_) + q * 8) * 4; \
    a0_ = *reinterpret_cast<const int4*>(rowb_ + (cb0_ ^ sw_)); \
    a1_ = *reinterpret_cast<const int4*>(rowb_ + ((cb0_ + 16) ^ sw_)); \
  }

#define MFMA9(a0_, a1_, B_) { \
    union { bf16x8 v; unsigned int u[4]; } af; \
    af.u[0] = (unsigned int)((a0_).x | ((a0_).y << 16)) * 0x3F80u; \
    af.u[1] = (unsigned int)((a0_).z | ((a0_).w << 16)) * 0x3F80u; \
    af.u[2] = (unsigned int)((a1_).x | ((a1_).y << 16)) * 0x3F80u; \
    af.u[3] = (unsigned int)((a1_).z | ((a1_).w << 16)) * 0x3F80u; \
    _Pragma("unroll") \
    for (int nf = 0; nf < 9; nf++) \
      acc[nf] = __builtin_amdgcn_mfma_f32_16x16x32_bf16(af.v, B_[nf], acc[nf], 0, 0, 0); \
  }

  bf16x8 Be[9], Bo[9];
  int4 a0, a1;

  // prologue: stage tile 0, prefetch windows 0,1; drain; sync
  STAGE_A(0, 0);
  LOAD_B(Be, 0);
  LOAD_B(Bo, 1);
  __syncthreads();

  for (int t = 0; t < 16; ++t) {
    const int buf = t & 1;
    if (t < 15) STAGE_A((t + 1) * 64, buf ^ 1);
    // window 2t (even)
    AFRAG(buf, 0, a0, a1);
    MFMA9(a0, a1, Be);
    if (t < 15) LOAD_B(Be, 2 * t + 2);
    // window 2t+1 (odd)
    AFRAG(buf, 32, a0, a1);
    MFMA9(a0, a1, Bo);
    if (t < 15) LOAD_B(Bo, 2 * t + 3);
    __syncthreads();
  }
#undef STAGE_A
#undef LOAD_B
#undef AFRAG
#undef MFMA9

  float* Pp = P + (size_t)s * N_NODES * NPAD;
  const int colb = lane & 15;
  #pragma unroll
  for (int nf = 0; nf < 9; nf++) {
    // nf==8 covers cols 128..143; only col 128 (Z) is ever read — skip pads.
    if (nf == 8 && colb != 0) continue;
    #pragma unroll
    for (int r = 0; r < 4; r++) {
      const int grow = bm * 64 + w * 16 + q * 4 + r;   // C/D: row=(lane>>4)*4+r
      Pp[(size_t)grow * NPAD + nf * 16 + colb] = acc[nf][r];
    }
  }
}

// ---- K6: reduce split-K, divide, residual, ELU ----------------------------
__global__ __launch_bounds__(256) void k6_fin(const float* __restrict__ P,
    const float* __restrict__ x, float* __restrict__ out) {
  const int gid = blockIdx.x * 256 + threadIdx.x;
  const int i = gid >> 7, d = gid & 127;
  const size_t base = (size_t)i * NPAD;
  float num = 0.f, Z = 0.f;
  #pragma unroll
  for (int s = 0; s < NSPLIT; s++) {
    num += P[(size_t)s * N_NODES * NPAD + base + d];
    Z   += P[(size_t)s * N_NODES * NPAD + base + 128];
  }
  const float agg = (Z > 0.f) ? num / Z : 0.f;   // empty row never occurs here
  const float v = x[(size_t)i * FOUT + d] + agg;
  out[gid] = (v > 0.f) ? v : expm1f(v);
}

extern "C" void kernel_launch(void* const* d_in, const int* in_sizes, int n_in,
                              void* d_out, int out_size, void* d_ws, size_t ws_size,
                              hipStream_t stream) {
  const float* input = (const float*)d_in[0];
  const int*   adj   = (const int*)d_in[1];
  const float* Wfc   = (const float*)d_in[2];
  const float* bfc   = (const float*)d_in[3];
  // d_in[4], d_in[5] (w_ax, b_ax) cancel in the row softmax — unused.
  const float* wan   = (const float*)d_in[6];
  const float* ban   = (const float*)d_in[7];

  char* ws = (char*)d_ws;
  float*          x    = (float*)(ws + X_OFF);
  float*          t    = (float*)(ws + T_OFF);
  float*          pmax = (float*)(ws + PMAX_OFF);
  float*          gmax = (float*)(ws + GMAX_OFF);
  unsigned short* Yf   = (unsigned short*)(ws + YT_OFF);
  float*          P    = (float*)(ws + P_OFF);
  float*          out  = (float*)d_out;

  k1_fc  <<<dim3(512),         dim3(256), 0, stream>>>(input, Wfc, bfc, x);
  k2_att <<<dim3(256),         dim3(256), 0, stream>>>(x, wan, ban, t, pmax);
  k3_gmax<<<dim3(1),           dim3(64),  0, stream>>>(pmax, gmax);
  k4_y   <<<dim3(128),         dim3(256), 0, stream>>>(x, t, gmax, Yf);
  k5_gemm<<<dim3(128, NSPLIT), dim3(256), 0, stream>>>(adj, Yf, P);
  k6_fin <<<dim3(4096),        dim3(256), 0, stream>>>(P, x, out);
}

// Round 6
// 454.851 us; speedup vs baseline: 1.1821x; 1.0100x over previous
//
#include <hip/hip_runtime.h>
#include <hip/hip_bf16.h>
#include <math.h>

// ---------------------------------------------------------------------------
// GraphAttentionLayer on MI355X.
// Math: softmax over (s_i + t_j) masked by adj  ==> s_i cancels row-wise.
//   e_j   = exp(t_j - gmax)
//   agg_i = (A @ (e*x))_i / (A @ e)_i          (A = adj as 0/1)
//   out   = elu(x + agg)
// => dense bf16 MFMA GEMM  A[8192x8192] @ Y[8192x144], split-K=8.
// NEW: adj is packed to 1 bit/entry by k0 (pure 268MB stream at ~peak BW);
// k5 reads the 8MB bitmask from L2, expands bits->bf16 in VALU, no LDS,
// no barriers — register-dataflow MFMA with 2-window B prefetch.
// ---------------------------------------------------------------------------

using f32x4  = __attribute__((ext_vector_type(4))) float;
using bf16x8 = __attribute__((ext_vector_type(8))) short;

#define N_NODES 8192
#define FIN     256
#define FOUT    128
#define NPAD    144
#define NSPLIT  8
#define KCHUNK  (N_NODES / NSPLIT)   // 1024

// workspace layout (bytes)
#define X_OFF    0u                                   // 8192*128 f32  = 4 MB
#define T_OFF    (X_OFF + N_NODES*FOUT*4u)            // 8192 f32
#define PMAX_OFF (T_OFF + N_NODES*4u)                 // 256 f32
#define GMAX_OFF (PMAX_OFF + 1024u)                   // 1 f32
#define YT_OFF   (GMAX_OFF + 512u)                    // 144*8192 bf16 = 2.36 MB
#define P_OFF    (YT_OFF + (size_t)NPAD*N_NODES*2u)   // 8*8192*144 f32 = 37.7 MB
#define ADJP_OFF (P_OFF + (size_t)NSPLIT*N_NODES*NPAD*4u)  // 8192*128 B = 1 MB

__device__ __forceinline__ unsigned short f2bf(float f) {
  unsigned int u = __float_as_uint(f);
  unsigned int r = (u + 0x7FFFu + ((u >> 16) & 1u)) >> 16;   // RNE
  return (unsigned short)r;
}

// ---- K0: pack adj int32 0/1 -> 1 bit/col. bit j of u64 g  <->  col g*64+j --
// One wave per row; __ballot gives exactly the MFMA-frag bit order.
__global__ __launch_bounds__(256) void k0_pack(const int* __restrict__ adj,
    unsigned long long* __restrict__ adjP) {
  const int lane = threadIdx.x & 63, w = threadIdx.x >> 6;
  const int row = blockIdx.x * 4 + w;
  const int* src = adj + (size_t)row * N_NODES;
  unsigned long long mine = 0;
  for (int h = 0; h < 2; ++h) {
    #pragma unroll 16
    for (int g = 0; g < 64; ++g) {
      int v = src[h * 4096 + g * 64 + lane];
      unsigned long long m = __ballot(v != 0);
      if (lane == g) mine = m;
    }
    adjP[(size_t)row * 128 + h * 64 + lane] = mine;
  }
}

// ---- K1: x = input @ W_fc + b_fc  (f32 VALU GEMM, 16 rows/block) ----------
__global__ __launch_bounds__(256) void k1_fc(const float* __restrict__ in,
    const float* __restrict__ Wfc, const float* __restrict__ bfc,
    float* __restrict__ x) {
  __shared__ float sm[16 * FIN];
  const int tid = threadIdx.x;
  const int r0  = blockIdx.x * 16;
  const float4* gin = reinterpret_cast<const float4*>(in + (size_t)r0 * FIN);
  float4* sm4 = reinterpret_cast<float4*>(sm);
  #pragma unroll
  for (int i = 0; i < 4; i++) sm4[i * 256 + tid] = gin[i * 256 + tid];
  __syncthreads();
  const int d = tid & 127, g = tid >> 7;
  const float bias = bfc[d];
  float acc[8];
  #pragma unroll
  for (int r = 0; r < 8; r++) acc[r] = bias;
  const float4* s4 = reinterpret_cast<const float4*>(sm);
  for (int k = 0; k < FIN; k += 4) {
    float w0 = Wfc[(k + 0) * FOUT + d];
    float w1 = Wfc[(k + 1) * FOUT + d];
    float w2 = Wfc[(k + 2) * FOUT + d];
    float w3 = Wfc[(k + 3) * FOUT + d];
    #pragma unroll
    for (int r = 0; r < 8; r++) {
      float4 iv = s4[((g * 8 + r) * FIN + k) >> 2];
      acc[r] = fmaf(iv.x, w0, acc[r]);
      acc[r] = fmaf(iv.y, w1, acc[r]);
      acc[r] = fmaf(iv.z, w2, acc[r]);
      acc[r] = fmaf(iv.w, w3, acc[r]);
    }
  }
  #pragma unroll
  for (int r = 0; r < 8; r++)
    x[(size_t)(r0 + g * 8 + r) * FOUT + d] = acc[r];
}

// ---- K2: t_j = x_j . w_an + b_an ; per-block max -> pmax (256 blocks) -----
__global__ __launch_bounds__(256) void k2_att(const float* __restrict__ x,
    const float* __restrict__ wan, const float* __restrict__ ban,
    float* __restrict__ t, float* __restrict__ pmax) {
  __shared__ float wm[4];
  const int tid = threadIdx.x, lane = tid & 63, w = tid >> 6;
  const float w0 = wan[lane], w1 = wan[lane + 64];
  const float bb = ban[0];
  float tmax = -1e30f;
  const int rbase = blockIdx.x * 32 + w * 8;
  for (int rr = 0; rr < 8; rr++) {
    const int row = rbase + rr;
    float p = x[(size_t)row * FOUT + lane] * w0
            + x[(size_t)row * FOUT + 64 + lane] * w1;
    #pragma unroll
    for (int m = 1; m < 64; m <<= 1) p += __shfl_xor(p, m);
    const float tv = p + bb;
    if (lane == 0) t[row] = tv;
    tmax = fmaxf(tmax, tv);
  }
  if (lane == 0) wm[w] = tmax;
  __syncthreads();
  if (tid == 0)
    pmax[blockIdx.x] = fmaxf(fmaxf(wm[0], wm[1]), fmaxf(wm[2], wm[3]));
}

// ---- K3: gmax = max(pmax[0..255]) -----------------------------------------
__global__ void k3_gmax(const float* __restrict__ pmax, float* __restrict__ gmax) {
  float v = fmaxf(fmaxf(pmax[threadIdx.x], pmax[threadIdx.x + 64]),
                  fmaxf(pmax[threadIdx.x + 128], pmax[threadIdx.x + 192]));
  #pragma unroll
  for (int m = 1; m < 64; m <<= 1) v = fmaxf(v, __shfl_xor(v, m));
  if (threadIdx.x == 0) gmax[0] = v;
}

// ---- K4: build Yf in MFMA B-fragment order via LDS transpose --------------
__global__ __launch_bounds__(256) void k4_y(const float* __restrict__ x,
    const float* __restrict__ t, const float* __restrict__ gmax,
    unsigned short* __restrict__ Yf) {
  __shared__ unsigned short sm[NPAD * 64];
  const int tid = threadIdx.x, lane = tid & 63, w = tid >> 6;
  const int jj = lane, j = blockIdx.x * 64 + jj;
  const float e = expf(t[j] - gmax[0]);
  const float4* x4 = reinterpret_cast<const float4*>(x + (size_t)j * FOUT + w * 32);
  #pragma unroll
  for (int dd = 0; dd < 8; dd++) {
    float4 xv = x4[dd];
    const int c = w * 32 + dd * 4;
    sm[(c + 0) * 64 + jj] = f2bf(e * xv.x);
    sm[(c + 1) * 64 + jj] = f2bf(e * xv.y);
    sm[(c + 2) * 64 + jj] = f2bf(e * xv.z);
    sm[(c + 3) * 64 + jj] = f2bf(e * xv.w);
  }
  #pragma unroll
  for (int i = 0; i < 4; i++) {     // cols 128..143: e in col 128, pads 0
    const int c = 128 + w * 4 + i;
    sm[c * 64 + jj] = (c == 128) ? f2bf(e) : (unsigned short)0;
  }
  __syncthreads();
  for (int c5 = w; c5 < 18; c5 += 4) {
    const int wnd = c5 / 9, nf = c5 % 9;
    const int srcIdx = (nf * 16 + (lane & 15)) * 64 + wnd * 32 + (lane >> 4) * 8;
    bf16x8 v = *reinterpret_cast<const bf16x8*>(&sm[srcIdx]);
    const size_t Wg = (size_t)blockIdx.x * 2 + wnd;
    *reinterpret_cast<bf16x8*>(Yf + (Wg * 9 + nf) * 512 + lane * 8) = v;
  }
}

// ---- K5: P[s] = A[:, chunk_s] @ Y[chunk_s, :]   (bf16 MFMA, split-K) ------
// BM=64 (4 waves x 16 rows), BN=144 (9 n-frags). No LDS, no barriers.
// A: per-lane u64 bitmask per 64-k tile (L2-hot), expanded to bf16 in VALU.
// B: register prefetch 2 windows ahead (contiguous 1KB wave loads).
__global__ __launch_bounds__(256) void k5_gemm(
    const unsigned long long* __restrict__ adjP,
    const unsigned short* __restrict__ Yf, float* __restrict__ P) {
  const int tid  = threadIdx.x;
  const int lane = tid & 63, w = tid >> 6;
  const int bm = blockIdx.x, s = blockIdx.y;
  const int q  = lane >> 4, r = lane & 15;
  const int row_g = bm * 64 + w * 16 + r;
  // lane's packed A-strip for chunk s: one u64 per 64-k tile
  const unsigned long long* ap = adjP + (size_t)row_g * 128 + s * 16;
  const unsigned short* bbase = Yf + (size_t)s * 32 * 9 * 512 + lane * 8;
  const int qs = q * 8;   // bit shift for this lane's byte within a window

  f32x4 acc[9];
  #pragma unroll
  for (int nf = 0; nf < 9; nf++) acc[nf] = (f32x4){0.f, 0.f, 0.f, 0.f};

#define LOAD_B(dst_, wnd_) { \
    const unsigned short* p_ = bbase + (size_t)(wnd_) * 9 * 512; \
    _Pragma("unroll") \
    for (int nf = 0; nf < 9; nf++) \
      dst_[nf] = *reinterpret_cast<const bf16x8*>(p_ + nf * 512); \
  }

  // byte b_ (bits e=0..7 = A row elems k=qs+e) -> bf16 frag {0.0, 1.0}
#define MFMA_BITS(b_, B_) { \
    union { bf16x8 v; unsigned int u[4]; } af; \
    _Pragma("unroll") \
    for (int i2 = 0; i2 < 4; i2++) { \
      const unsigned bq = (b_) >> (2 * i2); \
      af.u[i2] = ((bq & 1u) ? 0x3F80u : 0u) | ((bq & 2u) ? 0x3F800000u : 0u); \
    } \
    _Pragma("unroll") \
    for (int nf = 0; nf < 9; nf++) \
      acc[nf] = __builtin_amdgcn_mfma_f32_16x16x32_bf16(af.v, B_[nf], acc[nf], 0, 0, 0); \
  }

  bf16x8 Be[9], Bo[9];
  unsigned long long Ac = ap[0];
  unsigned long long An = ap[1];
  LOAD_B(Be, 0);
  LOAD_B(Bo, 1);

  for (int t = 0; t < 16; ++t) {
    const unsigned lo = (unsigned)Ac, hi = (unsigned)(Ac >> 32);
    // even window (k = t*64 .. +31)
    const unsigned be_ = (lo >> qs) & 0xFFu;
    MFMA_BITS(be_, Be);
    if (t < 15) LOAD_B(Be, 2 * t + 2);
    // odd window (k = t*64+32 .. +63)
    const unsigned bo_ = (hi >> qs) & 0xFFu;
    MFMA_BITS(bo_, Bo);
    if (t < 15) LOAD_B(Bo, 2 * t + 3);
    Ac = An;
    if (t < 14) An = ap[t + 2];
  }
#undef LOAD_B
#undef MFMA_BITS

  float* Pp = P + (size_t)s * N_NODES * NPAD;
  const int colb = lane & 15;
  #pragma unroll
  for (int nf = 0; nf < 9; nf++) {
    // nf==8 covers cols 128..143; only col 128 (Z) is ever read — skip pads.
    if (nf == 8 && colb != 0) continue;
    #pragma unroll
    for (int rr = 0; rr < 4; rr++) {
      const int grow = bm * 64 + w * 16 + q * 4 + rr;  // C/D: row=(lane>>4)*4+r
      Pp[(size_t)grow * NPAD + nf * 16 + colb] = acc[nf][rr];
    }
  }
}

// ---- K6: reduce split-K, divide, residual, ELU ----------------------------
__global__ __launch_bounds__(256) void k6_fin(const float* __restrict__ P,
    const float* __restrict__ x, float* __restrict__ out) {
  const int gid = blockIdx.x * 256 + threadIdx.x;
  const int i = gid >> 7, d = gid & 127;
  const size_t base = (size_t)i * NPAD;
  float num = 0.f, Z = 0.f;
  #pragma unroll
  for (int s = 0; s < NSPLIT; s++) {
    num += P[(size_t)s * N_NODES * NPAD + base + d];
    Z   += P[(size_t)s * N_NODES * NPAD + base + 128];
  }
  const float agg = (Z > 0.f) ? num / Z : 0.f;   // empty row never occurs here
  const float v = x[(size_t)i * FOUT + d] + agg;
  out[gid] = (v > 0.f) ? v : expm1f(v);
}

extern "C" void kernel_launch(void* const* d_in, const int* in_sizes, int n_in,
                              void* d_out, int out_size, void* d_ws, size_t ws_size,
                              hipStream_t stream) {
  const float* input = (const float*)d_in[0];
  const int*   adj   = (const int*)d_in[1];
  const float* Wfc   = (const float*)d_in[2];
  const float* bfc   = (const float*)d_in[3];
  // d_in[4], d_in[5] (w_ax, b_ax) cancel in the row softmax — unused.
  const float* wan   = (const float*)d_in[6];
  const float* ban   = (const float*)d_in[7];

  char* ws = (char*)d_ws;
  float*              x    = (float*)(ws + X_OFF);
  float*              t    = (float*)(ws + T_OFF);
  float*              pmax = (float*)(ws + PMAX_OFF);
  float*              gmax = (float*)(ws + GMAX_OFF);
  unsigned short*     Yf   = (unsigned short*)(ws + YT_OFF);
  float*              P    = (float*)(ws + P_OFF);
  unsigned long long* adjP = (unsigned long long*)(ws + ADJP_OFF);
  float*              out  = (float*)d_out;

  k0_pack<<<dim3(2048),        dim3(256), 0, stream>>>(adj, adjP);
  k1_fc  <<<dim3(512),         dim3(256), 0, stream>>>(input, Wfc, bfc, x);
  k2_att <<<dim3(256),         dim3(256), 0, stream>>>(x, wan, ban, t, pmax);
  k3_gmax<<<dim3(1),           dim3(64),  0, stream>>>(pmax, gmax);
  k4_y   <<<dim3(128),         dim3(256), 0, stream>>>(x, t, gmax, Yf);
  k5_gemm<<<dim3(128, NSPLIT), dim3(256), 0, stream>>>(adjP, Yf, P);
  k6_fin <<<dim3(4096),        dim3(256), 0, stream>>>(P, x, out);
}